// Round 12
// baseline (300.702 us; speedup 1.0000x reference)
//
#include <hip/hip_runtime.h>
#include <hip/hip_bf16.h>

#define BATCH 4
#define SEQ   1024
#define DIM   1024
#define NH    16
#define DH    64
#define DFF   4096
#define MTOK  (BATCH*SEQ)   // 4096 token rows

// log2(e)/8 : folded into Q so attention softmax runs in base-2 (exact).
#define QSCALE 0.1803368801111204f

typedef __attribute__((ext_vector_type(8))) short  short8;
typedef __attribute__((ext_vector_type(4))) short  short4v;
typedef __attribute__((ext_vector_type(4))) float  floatx4;
typedef __attribute__((ext_vector_type(16))) float floatx16;
typedef __attribute__((ext_vector_type(4))) float  float4v;
typedef __attribute__((ext_vector_type(4))) int    int4v;

__device__ inline float bf2f(short s) {
    return __uint_as_float(((unsigned int)(unsigned short)s) << 16);
}
__device__ inline short f2bf(float f) {
    __hip_bfloat16 h = __float2bfloat16(f);
    return *reinterpret_cast<short*>(&h);
}

__device__ inline float wave_sum(float v) {
    #pragma unroll
    for (int off = 32; off >= 1; off >>= 1) v += __shfl_xor(v, off);
    return v;
}

// async global->LDS, 16B per lane; LDS dst = wave-uniform base + lane*16.
__device__ inline void async_ld16(short* lds, const short* g) {
    __builtin_amdgcn_global_load_lds(
        (const __attribute__((address_space(1))) void*)g,
        (__attribute__((address_space(3))) void*)lds, 16, 0, 0);
}

// ---------------------------------------------------------------------------
// Fused fp32->bf16 conversion of all 6 tensors in ONE launch.
// ---------------------------------------------------------------------------
__global__ __launch_bounds__(256) void convert_all(
    const float* __restrict__ sX,  short* __restrict__ dX,
    const float* __restrict__ sq,  short* __restrict__ dq,
    const float* __restrict__ sk,  short* __restrict__ dk,
    const float* __restrict__ sv,  short* __restrict__ dv,
    const float* __restrict__ s1,  short* __restrict__ d1,
    const float* __restrict__ s2,  short* __restrict__ d2)
{
    int cid = blockIdx.x * 256 + threadIdx.x;     // 0 .. 1966079
    const float* src; short* dst; int base;
    if      (cid <  524288) { src = sX; dst = dX; base = 0; }
    else if (cid <  655360) { src = sq; dst = dq; base = 524288; }
    else if (cid <  786432) { src = sk; dst = dk; base = 655360; }
    else if (cid <  917504) { src = sv; dst = dv; base = 786432; }
    else if (cid < 1441792) { src = s1; dst = d1; base = 917504; }
    else                    { src = s2; dst = d2; base = 1441792; }
    size_t i = (size_t)(cid - base) * 8;
    float4v f0 = *(const float4v*)(src + i);
    float4v f1 = *(const float4v*)(src + i + 4);
    short8 o;
    o[0]=f2bf(f0[0]); o[1]=f2bf(f0[1]); o[2]=f2bf(f0[2]); o[3]=f2bf(f0[3]);
    o[4]=f2bf(f1[0]); o[5]=f2bf(f1[1]); o[6]=f2bf(f1[2]); o[7]=f2bf(f1[3]);
    *(short8*)(dst + i) = o;
}

// ---------------------------------------------------------------------------
// NT GEMM, 128x128 tile, 32x32x16 MFMA, 2 blocks/CU, __syncthreads-only:
// C[M,N]=A[M,K]*B[N,K]^T, bf16, fp32 accum. BK=64, 256 thr = 4 waves
// (2M x 2N); per-wave C = 64x64 = 2x2 tiles of 32x32 (acc 2x2 x f32x16).
// LDS 64 KB: 2 buffers x {A 128x64, B 128x64} bf16, staged LINEARLY by
// global_load_lds, global source granule pre-permuted by the involution
// g ^= (row&7); ds_read applies the same XOR (rule 21).
//
// WHY 32x32: R4-R11 pinned at 46.7us across FIVE sync/occupancy schedules
// with 16x16x32 frags (32 MFMA + 16 ds_read per wave-tile). 32x32x16 halves
// MFMA issue count (16/tile) at the best-measured pipe (m119: 2495 TF =
// 99.8% of dense peak vs 2176 for 16x16). Same LDS bytes (16x b128).
// Operand layout: A/B lane l -> row l&31, k-half l>>5 (same lane pattern as
// the verified 16x16 path); C/D: col=lane&31, row=(reg&3)+8*(reg>>2)+
// 4*(lane>>5)  [HW-verified m74/m101].
//
// Per K-tile (ONE barrier): { stage kt+1 -> buf^1 (8x gload_lds);
//   read 16x b128 from buf; 16x mfma_32x32x16; __syncthreads() }
// __syncthreads waits vmcnt(0)+lgkmcnt(0)+barrier -> staged tile visible
// next iter; buf^1's readers drained at the PREVIOUS barrier. NT >= 1.
//
// EPI: 0 = QKV split store (Q pre-scaled by QSCALE; V written TRANSPOSED
//          into Vt[bh][d][key]); 1 = +bias,SELU;
//      3 = split-K bf16 partial store (blockIdx.z selects K quarter)
// ---------------------------------------------------------------------------
template<int EPI>
__global__ __launch_bounds__(256, 2) void gemm128d(
    const short* __restrict__ A, const short* __restrict__ B,
    const float* __restrict__ bias, short* __restrict__ C, int N, int K)
{
    __shared__ __align__(16) short Ls[32768];      // 64 KB

    const int t    = threadIdx.x;                  // 0..255
    const int lane = t & 63;
    const int wave = t >> 6;
    const int l31  = lane & 31;
    const int hi   = lane >> 5;                    // 0..1 (k-half)
    const int wm   = wave & 1;                     // 0..1
    const int wn   = wave >> 1;                    // 0..1
    const int tm   = blockIdx.x * 128;
    const int tn   = blockIdx.y * 128;

    int kbase = 0, klen = K;
    if (EPI == 3) { klen = K >> 2; kbase = blockIdx.z * klen; }
    const int NT = klen >> 6;                      // K-tiles of 64

    // ---- staging precompute: inst i covers 16B granule G = i*256 + t ----
    // row = G>>3 = i*32 + (t>>3)  (i*32 == 0 mod 8 -> row&7 = (t>>3)&7)
    // physical granule p = t&7 holds logical granule p ^ (row&7).
    const int g8 = (((t & 7) ^ ((t >> 3) & 7)) << 3);
    int offR[4];
    #pragma unroll
    for (int i = 0; i < 4; i++) offR[i] = (i*32 + (t >> 3)) * K + g8;
    const short* Abase = A + (size_t)tm * K + kbase;
    const short* Bbase = B + (size_t)tn * K + kbase;
    short* dstb = &Ls[t * 8];   // + buf*16384 + i*2048 (+8192 for B)

    // ---- frag-read precompute (swizzled ds_read addresses) ----
    // read row rA = wm*64 + mt*32 + l31 (row&7 = l31&7); logical granule for
    // k-step ks is ks*2 + hi; physical = logical ^ (row&7).
    const int rowA = (wm*64 + l31) * 64;           // element base, A half
    const int rowB = 8192 + (wn*64 + l31) * 64;    // element base, B half
    int xg[4];
    #pragma unroll
    for (int ks = 0; ks < 4; ks++)
        xg[ks] = (((ks*2 + hi) ^ (l31 & 7)) << 3);

    short8 a[2][4], b[2][4];
    floatx16 acc[2][2];
    #pragma unroll
    for (int mt = 0; mt < 2; mt++)
        #pragma unroll
        for (int nt = 0; nt < 2; nt++)
            #pragma unroll
            for (int e = 0; e < 16; e++) acc[mt][nt][e] = 0.f;

#define STAGE_TILE(buf, k0) do { _Pragma("unroll")                    \
    for (int _i = 0; _i < 4; _i++) {                                  \
        async_ld16(dstb + (buf)*16384 + _i*2048,        Abase + offR[_i] + (k0)); \
        async_ld16(dstb + (buf)*16384 + 8192 + _i*2048, Bbase + offR[_i] + (k0)); \
    } } while (0)

#define LDAB(buf) do { _Pragma("unroll")                              \
    for (int _mt = 0; _mt < 2; _mt++) { _Pragma("unroll")             \
        for (int _ks = 0; _ks < 4; _ks++) {                           \
            a[_mt][_ks] = *(const short8*)&Ls[(buf)*16384 + rowA + _mt*2048 + xg[_ks]]; \
            b[_mt][_ks] = *(const short8*)&Ls[(buf)*16384 + rowB + _mt*2048 + xg[_ks]]; \
        } } } while (0)

// 16 MFMA; ks outer so same-acc reuse distance is 4 (pipe-friendly).
#define MM16() do { __builtin_amdgcn_s_setprio(1); _Pragma("unroll")  \
    for (int _ks = 0; _ks < 4; _ks++) { _Pragma("unroll")             \
        for (int _mt = 0; _mt < 2; _mt++) { _Pragma("unroll")         \
            for (int _nn = 0; _nn < 2; _nn++) {                       \
                acc[_mt][_nn] = __builtin_amdgcn_mfma_f32_32x32x16_bf16( \
                    a[_mt][_ks], b[_nn][_ks], acc[_mt][_nn], 0, 0, 0); \
            } } }                                                     \
    __builtin_amdgcn_s_setprio(0); } while (0)

    // ---- prologue: stage tile 0 into buf 0, drain + barrier
    STAGE_TILE(0, 0);
    __syncthreads();

    for (int kt = 0; kt < NT; ++kt) {
        const int cur = kt & 1;
        if (kt + 1 < NT) STAGE_TILE(cur ^ 1, (kt + 1) << 6);
        LDAB(cur);                                 // 16x ds_read_b128
        MM16();                                    // compiler waits lgkm
        __syncthreads();                           // drain vm+lgkm; handoff
    }

    const float SS = 1.0507009873554805f;
    const float SA = 1.6732632423543772f;

    // C/D layout (32x32): col = base + l31; row = base + g*8 + hi*4 + r,
    // acc element index = g*4 + r  (g = reg>>2, r = reg&3).
    #pragma unroll
    for (int mt = 0; mt < 2; mt++) {
        int rbase = tm + wm*64 + mt*32 + hi*4;
        #pragma unroll
        for (int nt = 0; nt < 2; nt++) {
            int col = tn + wn*64 + nt*32 + l31;
            if (EPI == 0 && (col >> 10) == 2) {
                // V: packed transposed store -> Vt[bh][d][key]
                int h = (col >> 6) & 15, d = col & 63;
                #pragma unroll
                for (int g = 0; g < 4; g++) {
                    int row0 = rbase + g*8;
                    int bb = row0 >> 10, key = row0 & 1023;
                    short4v pv;
                    #pragma unroll
                    for (int r = 0; r < 4; r++) pv[r] = f2bf(acc[mt][nt][g*4 + r]);
                    *(short4v*)&C[(size_t)2*MTOK*1024
                        + ((size_t)(bb*16 + h)*64 + d)*1024 + key] = pv;
                }
                continue;
            }
            #pragma unroll
            for (int g = 0; g < 4; g++) {
                #pragma unroll
                for (int r = 0; r < 4; r++) {
                    int row = rbase + g*8 + r;
                    float v = acc[mt][nt][g*4 + r];
                    if (EPI == 0) {
                        int which = col >> 10;
                        if (which == 0) v *= QSCALE;   // base-2 softmax fold
                        C[(size_t)which * ((size_t)MTOK*1024)
                          + (size_t)row * 1024 + (col & 1023)] = f2bf(v);
                    } else if (EPI == 1) {
                        v += bias[col];
                        v = (v > 0.f) ? SS * v
                                      : SS * SA * (exp2f(v * 1.44269504f) - 1.f);
                        C[(size_t)row * N + col] = f2bf(v);
                    } else {   // EPI == 3: raw bf16 partial, quarter z
                        C[(size_t)blockIdx.z * ((size_t)MTOK*N)
                          + (size_t)row * N + col] = f2bf(v);
                    }
                }
            }
        }
    }
#undef STAGE_TILE
#undef LDAB
#undef MM16
}

// ---------------------------------------------------------------------------
// MFMA flash attention, QBLK=64 (R11 was 128: occupancy 10.6%, tail-bound).
// 64-row Q-tile, 4 waves x 16 q-rows; ping-pong LDS-staged K/V.
// Grid = (SEQ/64, BATCH*NH) = (16, 64) -> 1024 blocks, 3 blocks/CU (41 KB).
// Base-2 fixed-m softmax, ones-MFMA row-sum. V pre-transposed (Vt[bh][d][key]).
// SWAPPED QK^T: S = mfma(A=K, B=Q); P-store = ds_write_b64 packed.
// T2 SWIZZLE on Ks/Vs (both-sides, rule 21): source granule pre-permuted by
// g ^= (row&7); ds_read applies the same XOR. (R8: conflicts 4.18M -> 835K)
// ---------------------------------------------------------------------------
__global__ __launch_bounds__(256) void attn_kernel(
    const short* __restrict__ Q, const short* __restrict__ K,
    const short* __restrict__ Vt, short* __restrict__ CTX)
{
    __shared__ __align__(16) short Ks[2][64*64];    // [key][d], 2 x 8 KB
    __shared__ __align__(16) short Vs[2][64*64];    // [d][key], 2 x 8 KB
    __shared__ __align__(16) short Pl[4][16][72];   // [wave][qrow][key], 9 KB

    const int t    = threadIdx.x;
    const int lane = t & 63;
    const int wave = t >> 6;
    const int quad = lane >> 4;
    const int l15  = lane & 15;
    const int q0 = (gridDim.x - 1 - blockIdx.x) * 64;    // long blocks first
    const int bh = blockIdx.y;
    const int b  = bh >> 4;
    const int h  = bh & 15;

    const size_t headoff = (size_t)b * SEQ * DIM + (size_t)h * DH;
    const short* Qb  = Q + headoff;
    const short* Kb  = K + headoff;
    const short* Vtb = Vt + (size_t)bh * DH * SEQ;   // [d][key]

    const int wrow0 = q0 + wave*16;                  // wave's first q-row

    short8 aq[2];
    #pragma unroll
    for (int c = 0; c < 2; c++)
        aq[c] = *(const short8*)(Qb
            + (size_t)(wrow0 + l15) * DIM + c*32 + quad*8);

    short8 bones;
    {
        short v = (l15 == 0) ? (short)0x3F80 : (short)0;
        #pragma unroll
        for (int e = 0; e < 8; e++) bones[e] = v;
    }

    floatx4 o[4], ol;
    #pragma unroll
    for (int nt = 0; nt < 4; nt++) o[nt] = {0.f, 0.f, 0.f, 0.f};
    ol = {0.f, 0.f, 0.f, 0.f};

    // stage with pre-swizzled source granule: physical granule (t&7) at row
    // r=(t>>3)+p*32 receives logical granule (t&7)^(r&7); p*32 = 0 mod 8.
    const int swz = (((t & 7) ^ ((t >> 3) & 7))) * 8;
    auto stage = [&](int j0, int sb) {
        #pragma unroll
        for (int p = 0; p < 2; p++) {
            async_ld16(Ks[sb] + (t + p*256)*8,
                       Kb + (size_t)(j0 + (t>>3) + p*32) * DIM + swz);
            async_ld16(Vs[sb] + (t + p*256)*8,
                       Vtb + (size_t)((t>>3) + p*32) * SEQ + j0 + swz);
        }
    };

    const int jend = q0 + 64;
    stage(0, 0);
    __syncthreads();

    int sb = 0;
    for (int j0 = 0; j0 < jend; j0 += 64) {
        if (j0 + 64 < jend) stage(j0 + 64, sb ^ 1);

        if (j0 <= wrow0 + 15) {              // not fully masked for this wave
            floatx4 s[4];
            #pragma unroll
            for (int nt = 0; nt < 4; nt++) s[nt] = {0.f, 0.f, 0.f, 0.f};
            // SWAPPED: A = K-frag, B = Q-frag -> C row = key, col = q.
            // K-frag read: row = nt*16+l15, granule (c*4+quad)^(row&7).
            #pragma unroll
            for (int c = 0; c < 2; c++) {
                #pragma unroll
                for (int nt = 0; nt < 4; nt++) {
                    short8 bk = *(const short8*)&Ks[sb][(nt*16 + l15)*64
                                  + ((c*4 + quad) ^ (l15 & 7))*8];
                    s[nt] = __builtin_amdgcn_mfma_f32_16x16x32_bf16(bk, aq[c], s[nt], 0, 0, 0);
                }
            }

            if (j0 + 63 > wrow0) {           // diagonal region: causal mask
                int rowq = wrow0 + l15;                      // q = col
                #pragma unroll
                for (int nt = 0; nt < 4; nt++) {
                    #pragma unroll
                    for (int r = 0; r < 4; r++) {
                        int key = j0 + nt*16 + quad*4 + r;   // key = row
                        if (key > rowq) s[nt][r] = -1.0e38f;
                    }
                }
            }

            // packed P-store: 4 consecutive keys per lane -> one b64 write
            #pragma unroll
            for (int nt = 0; nt < 4; nt++) {
                short4v pv;
                #pragma unroll
                for (int r = 0; r < 4; r++)
                    pv[r] = f2bf(exp2f(s[nt][r]));
                *(short4v*)&Pl[wave][l15][nt*16 + quad*4] = pv;
            }

            #pragma unroll
            for (int c = 0; c < 2; c++) {
                short8 ap = *(const short8*)&Pl[wave][l15][c*32 + quad*8];
                #pragma unroll
                for (int nt = 0; nt < 4; nt++) {
                    // V-frag read: row (=d) = nt*16+l15, same XOR swizzle.
                    short8 bv = *(const short8*)&Vs[sb][(nt*16 + l15)*64
                                  + ((c*4 + quad) ^ (l15 & 7))*8];
                    o[nt] = __builtin_amdgcn_mfma_f32_16x16x32_bf16(ap, bv, o[nt], 0, 0, 0);
                }
                ol = __builtin_amdgcn_mfma_f32_16x16x32_bf16(ap, bones, ol, 0, 0, 0);
            }
        }

        __syncthreads();                     // drains vmcnt after compute
        sb ^= 1;
    }

    float linv[4];
    #pragma unroll
    for (int r = 0; r < 4; r++)
        linv[r] = 1.f / __shfl(ol[r], lane & 48);
    #pragma unroll
    for (int nt = 0; nt < 4; nt++) {
        #pragma unroll
        for (int r = 0; r < 4; r++) {
            int rowq = wrow0 + quad*4 + r;
            int d    = nt*16 + l15;
            CTX[(size_t)b * SEQ * DIM + (size_t)rowq * DIM + h*DH + d]
                = f2bf(o[nt][r] * linv[r]);
        }
    }
}

// ---------------------------------------------------------------------------
// LN1: row LayerNorm over D=1024 of (X fp32 + CTX bf16), bf16 out.
// ---------------------------------------------------------------------------
__global__ __launch_bounds__(256) void ln1_kernel(
    const float* __restrict__ X, const short* __restrict__ ctx,
    const float* __restrict__ g, const float* __restrict__ bvec,
    short* __restrict__ out)
{
    __shared__ float red[8];
    const size_t base = (size_t)blockIdx.x * DIM;
    const int wave = threadIdx.x >> 6;

    float x[4];
    float sum = 0.f, sq = 0.f;
    #pragma unroll
    for (int i = 0; i < 4; i++) {
        int idx = threadIdx.x + i*256;
        float v = X[base + idx] + bf2f(ctx[base + idx]);
        x[i] = v; sum += v; sq += v*v;
    }
    sum = wave_sum(sum); sq = wave_sum(sq);
    if ((threadIdx.x & 63) == 0) { red[wave] = sum; red[4 + wave] = sq; }
    __syncthreads();
    float s1 = red[0] + red[1] + red[2] + red[3];
    float s2 = red[4] + red[5] + red[6] + red[7];
    float mean = s1 * (1.f / DIM);
    float var  = s2 * (1.f / DIM) - mean * mean;
    float rstd = rsqrtf(var + 1e-5f);
    #pragma unroll
    for (int i = 0; i < 4; i++) {
        int idx = threadIdx.x + i*256;
        out[base + idx] = f2bf((x[i] - mean) * rstd * g[idx] + bvec[idx]);
    }
}

// ---------------------------------------------------------------------------
// LN2 fused with split-K reduce: x = P0+P1+P2+P3 (bf16 partials) + bias +
// X1 (residual), then LayerNorm, fp32 out to d_out.
// ---------------------------------------------------------------------------
__global__ __launch_bounds__(256) void ln2_fused(
    const short* __restrict__ P, const float* __restrict__ bias,
    const short* __restrict__ x1, const float* __restrict__ g,
    const float* __restrict__ bvec, float* __restrict__ out)
{
    __shared__ float red[8];
    const size_t base = (size_t)blockIdx.x * DIM;
    const size_t E4 = (size_t)MTOK * 1024;
    const int wave = threadIdx.x >> 6;

    float x[4];
    float sum = 0.f, sq = 0.f;
    #pragma unroll
    for (int i = 0; i < 4; i++) {
        int idx = threadIdx.x + i*256;
        size_t p = base + idx;
        float v = bf2f(P[p]) + bf2f(P[E4 + p]) + bf2f(P[2*E4 + p])
                + bf2f(P[3*E4 + p]) + bias[idx] + bf2f(x1[p]);
        x[i] = v; sum += v; sq += v*v;
    }
    sum = wave_sum(sum); sq = wave_sum(sq);
    if ((threadIdx.x & 63) == 0) { red[wave] = sum; red[4 + wave] = sq; }
    __syncthreads();
    float s1 = red[0] + red[1] + red[2] + red[3];
    float s2 = red[4] + red[5] + red[6] + red[7];
    float mean = s1 * (1.f / DIM);
    float var  = s2 * (1.f / DIM) - mean * mean;
    float rstd = rsqrtf(var + 1e-5f);
    #pragma unroll
    for (int i = 0; i < 4; i++) {
        int idx = threadIdx.x + i*256;
        out[base + idx] = (x[i] - mean) * rstd * g[idx] + bvec[idx];
    }
}

// ---------------------------------------------------------------------------
// Workspace (102 MB -- exactly R2's proven-safe footprint).
// Q | K | Vt contiguous (fused QKV epilogue). P = 4 split-K partials.
// d_out is float* (verified round 4).
// ---------------------------------------------------------------------------
extern "C" void kernel_launch(void* const* d_in, const int* in_sizes, int n_in,
                              void* d_out, int out_size, void* d_ws, size_t ws_size,
                              hipStream_t stream)
{
    const float* X   = (const float*)d_in[0];
    const float* wq  = (const float*)d_in[1];
    const float* wk  = (const float*)d_in[2];
    const float* wv  = (const float*)d_in[3];
    const float* g1  = (const float*)d_in[4];
    const float* b1  = (const float*)d_in[5];
    const float* w1  = (const float*)d_in[6];
    const float* bb1 = (const float*)d_in[7];
    const float* w2  = (const float*)d_in[8];
    const float* bb2 = (const float*)d_in[9];
    const float* g2  = (const float*)d_in[10];
    const float* b2  = (const float*)d_in[11];

    short* ws = (short*)d_ws;
    const size_t E1 = 1048576, E4 = 4194304;
    size_t o = 0;
    short* Xb    = ws + o; o += E4;
    short* wqkvb = ws + o; o += 3*E1;
    short* w1b   = ws + o; o += E4;
    short* w2b   = ws + o; o += E4;
    short* Q     = ws + o; o += E4;   // Q | K | Vt contiguous
    short* Kb    = ws + o; o += E4;
    short* Vt    = ws + o; o += E4;
    short* CTX   = ws + o; o += E4;
    short* X1    = ws + o; o += E4;
    short* P     = ws + o; o += 4*E4; // split-K=4 partials (bf16)
    short* Hf    = Q;                 // 16M elems, overlays Q..CTX

    dim3 blk(256);
    convert_all<<<dim3(7680), blk, 0, stream>>>(
        X, Xb, wq, wqkvb, wk, wqkvb + E1, wv, wqkvb + 2*E1,
        w1, w1b, w2, w2b);

    gemm128d<0><<<dim3(MTOK/128, 3072/128), blk, 0, stream>>>(
        Xb, wqkvb, nullptr, Q, 3072, DIM);
    attn_kernel<<<dim3(SEQ/64, BATCH*NH), blk, 0, stream>>>(Q, Kb, Vt, CTX);
    ln1_kernel<<<dim3(MTOK), blk, 0, stream>>>(X, CTX, g1, b1, X1);
    gemm128d<1><<<dim3(MTOK/128, DFF/128), blk, 0, stream>>>(
        X1, w1b, bb1, Hf, DFF, DIM);
    gemm128d<3><<<dim3(MTOK/128, DIM/128, 4), blk, 0, stream>>>(
        Hf, w2b, nullptr, P, DIM, DFF);
    ln2_fused<<<dim3(MTOK), blk, 0, stream>>>(P, bb2, X1, g2, b2, (float*)d_out);
}

// Round 13
// 287.503 us; speedup vs baseline: 1.0459x; 1.0459x over previous
//
#include <hip/hip_runtime.h>
#include <hip/hip_bf16.h>

#define BATCH 4
#define SEQ   1024
#define DIM   1024
#define NH    16
#define DH    64
#define DFF   4096
#define MTOK  (BATCH*SEQ)   // 4096 token rows

// log2(e)/8 : folded into Q so attention softmax runs in base-2 (exact).
#define QSCALE 0.1803368801111204f

typedef __attribute__((ext_vector_type(8))) short  short8;
typedef __attribute__((ext_vector_type(4))) short  short4v;
typedef __attribute__((ext_vector_type(4))) float  floatx4;
typedef __attribute__((ext_vector_type(4))) float  float4v;
typedef __attribute__((ext_vector_type(4))) int    int4v;

__device__ inline float bf2f(short s) {
    return __uint_as_float(((unsigned int)(unsigned short)s) << 16);
}
__device__ inline short f2bf(float f) {
    __hip_bfloat16 h = __float2bfloat16(f);
    return *reinterpret_cast<short*>(&h);
}

__device__ inline float wave_sum(float v) {
    #pragma unroll
    for (int off = 32; off >= 1; off >>= 1) v += __shfl_xor(v, off);
    return v;
}

// async global->LDS, 16B per lane; LDS dst = wave-uniform base + lane*16.
__device__ inline void async_ld16(short* lds, const short* g) {
    __builtin_amdgcn_global_load_lds(
        (const __attribute__((address_space(1))) void*)g,
        (__attribute__((address_space(3))) void*)lds, 16, 0, 0);
}

// ---------------------------------------------------------------------------
// Fused fp32->bf16 conversion of all 6 tensors in ONE launch.
// ---------------------------------------------------------------------------
__global__ __launch_bounds__(256) void convert_all(
    const float* __restrict__ sX,  short* __restrict__ dX,
    const float* __restrict__ sq,  short* __restrict__ dq,
    const float* __restrict__ sk,  short* __restrict__ dk,
    const float* __restrict__ sv,  short* __restrict__ dv,
    const float* __restrict__ s1,  short* __restrict__ d1,
    const float* __restrict__ s2,  short* __restrict__ d2)
{
    int cid = blockIdx.x * 256 + threadIdx.x;     // 0 .. 1966079
    const float* src; short* dst; int base;
    if      (cid <  524288) { src = sX; dst = dX; base = 0; }
    else if (cid <  655360) { src = sq; dst = dq; base = 524288; }
    else if (cid <  786432) { src = sk; dst = dk; base = 655360; }
    else if (cid <  917504) { src = sv; dst = dv; base = 786432; }
    else if (cid < 1441792) { src = s1; dst = d1; base = 917504; }
    else                    { src = s2; dst = d2; base = 1441792; }
    size_t i = (size_t)(cid - base) * 8;
    float4v f0 = *(const float4v*)(src + i);
    float4v f1 = *(const float4v*)(src + i + 4);
    short8 o;
    o[0]=f2bf(f0[0]); o[1]=f2bf(f0[1]); o[2]=f2bf(f0[2]); o[3]=f2bf(f0[3]);
    o[4]=f2bf(f1[0]); o[5]=f2bf(f1[1]); o[6]=f2bf(f1[2]); o[7]=f2bf(f1[3]);
    *(short8*)(dst + i) = o;
}

// ---------------------------------------------------------------------------
// NT GEMM, 128x128 tile, 16x16x32 MFMA, 2 blocks/CU, __syncthreads-only
// (R11-verified: 46.7us, conflicts 0 -- R12's 32x32 frags regressed to 58us
// with 4.19M conflicts; the quad-based 16x16 read pattern is the
// conflict-free one). C[M,N]=A[M,K]*B[N,K]^T, bf16, fp32 accum. BK=64,
// 256 thr = 4 waves (2M x 2N), per-wave C=64x64 (16 acc).
// LDS 64 KB: 2 buffers x {A 128x64, B 128x64} bf16, staged LINEARLY by
// global_load_lds, global source granule pre-permuted by the involution
// g ^= (row&7); ds_read applies the same XOR (rule 21).
//
// Per K-tile (ONE barrier): { stage kt+1 -> buf^1 (8x gload_lds);
//   read 16x b128 from buf; 32 MFMA; __syncthreads() }
// __syncthreads waits vmcnt(0)+lgkmcnt(0)+barrier -> staged tile visible
// next iter; buf^1's readers drained at the PREVIOUS barrier. NT >= 1.
//
// EPI: 0 = QKV split store (Q pre-scaled by QSCALE; V written TRANSPOSED
//          into Vt[bh][d][key]); 1 = +bias,SELU;
//      3 = split-K bf16 partial store (blockIdx.z selects K quarter)
// ---------------------------------------------------------------------------
template<int EPI>
__global__ __launch_bounds__(256, 2) void gemm128d(
    const short* __restrict__ A, const short* __restrict__ B,
    const float* __restrict__ bias, short* __restrict__ C, int N, int K)
{
    __shared__ __align__(16) short Ls[32768];      // 64 KB

    const int t    = threadIdx.x;                  // 0..255
    const int lane = t & 63;
    const int wave = t >> 6;
    const int quad = lane >> 4;
    const int l15  = lane & 15;
    const int wm   = wave & 1;                     // 0..1
    const int wn   = wave >> 1;                    // 0..1
    const int tm   = blockIdx.x * 128;
    const int tn   = blockIdx.y * 128;

    int kbase = 0, klen = K;
    if (EPI == 3) { klen = K >> 2; kbase = blockIdx.z * klen; }
    const int NT = klen >> 6;                      // K-tiles of 64

    // ---- staging precompute: inst i covers 16B granule G = i*256 + t ----
    // row = G>>3 = i*32 + (t>>3)  (i*32 == 0 mod 8 -> row&7 = (t>>3)&7)
    // physical granule p = t&7 holds logical granule p ^ (row&7).
    const int g8 = (((t & 7) ^ ((t >> 3) & 7)) << 3);
    int offR[4];
    #pragma unroll
    for (int i = 0; i < 4; i++) offR[i] = (i*32 + (t >> 3)) * K + g8;
    const short* Abase = A + (size_t)tm * K + kbase;
    const short* Bbase = B + (size_t)tn * K + kbase;
    short* dstb = &Ls[t * 8];   // + buf*16384 + i*2048 (+8192 for B)

    // ---- frag-read precompute (swizzled ds_read addresses) ----
    const int xa  = (wm*64 + l15) * 64;            // A logical row base
    const int xb  = (wn*64 + l15) * 64;            // B logical row base
    const int sw  = l15 & 7;
    const int xc0 = ((quad ^ sw) << 3);            // ksub c=0 granule
    const int xc1 = (((4 + quad) ^ sw) << 3);      // ksub c=1 granule

    short8 a[4][2], b[4][2];
    floatx4 acc[4][4];
    #pragma unroll
    for (int mt = 0; mt < 4; mt++)
        #pragma unroll
        for (int nt = 0; nt < 4; nt++) acc[mt][nt] = {0.f, 0.f, 0.f, 0.f};

#define STAGE_TILE(buf, k0) do { _Pragma("unroll")                    \
    for (int _i = 0; _i < 4; _i++) {                                  \
        async_ld16(dstb + (buf)*16384 + _i*2048,        Abase + offR[_i] + (k0)); \
        async_ld16(dstb + (buf)*16384 + 8192 + _i*2048, Bbase + offR[_i] + (k0)); \
    } } while (0)

#define LDAB(buf) do { _Pragma("unroll")                              \
    for (int _mt = 0; _mt < 4; _mt++) {                               \
        a[_mt][0] = *(const short8*)&Ls[(buf)*16384 + xa + _mt*1024 + xc0]; \
        a[_mt][1] = *(const short8*)&Ls[(buf)*16384 + xa + _mt*1024 + xc1]; \
        b[_mt][0] = *(const short8*)&Ls[(buf)*16384 + 8192 + xb + _mt*1024 + xc0]; \
        b[_mt][1] = *(const short8*)&Ls[(buf)*16384 + 8192 + xb + _mt*1024 + xc1]; \
    } } while (0)

// 32 MFMA, c outermost so consecutive MFMAs never hit the same accumulator.
#define MM32() do { __builtin_amdgcn_s_setprio(1); _Pragma("unroll")  \
    for (int _c = 0; _c < 2; _c++) { _Pragma("unroll")                \
        for (int _mt = 0; _mt < 4; _mt++) { _Pragma("unroll")         \
            for (int _nn = 0; _nn < 4; _nn++) {                       \
                acc[_mt][_nn] = __builtin_amdgcn_mfma_f32_16x16x32_bf16( \
                    a[_mt][_c], b[_nn][_c], acc[_mt][_nn], 0, 0, 0);  \
            } } }                                                     \
    __builtin_amdgcn_s_setprio(0); } while (0)

    // ---- prologue: stage tile 0 into buf 0, drain + barrier
    STAGE_TILE(0, 0);
    __syncthreads();

    for (int kt = 0; kt < NT; ++kt) {
        const int cur = kt & 1;
        if (kt + 1 < NT) STAGE_TILE(cur ^ 1, (kt + 1) << 6);
        LDAB(cur);                                 // 16x ds_read_b128
        MM32();                                    // compiler waits lgkm
        __syncthreads();                           // drain vm+lgkm; handoff
    }

    const float SS = 1.0507009873554805f;
    const float SA = 1.6732632423543772f;

    #pragma unroll
    for (int mt = 0; mt < 4; mt++) {
        int row0 = tm + wm*64 + mt*16 + quad*4;
        #pragma unroll
        for (int nt = 0; nt < 4; nt++) {
            int col = tn + wn*64 + nt*16 + l15;
            if (EPI == 0 && (col >> 10) == 2) {
                // V: packed transposed store -> Vt[bh][d][key]
                int h = (col >> 6) & 15, d = col & 63;
                int bb = row0 >> 10, key = row0 & 1023;
                short4v pv;
                #pragma unroll
                for (int r = 0; r < 4; r++) pv[r] = f2bf(acc[mt][nt][r]);
                *(short4v*)&C[(size_t)2*MTOK*1024
                    + ((size_t)(bb*16 + h)*64 + d)*1024 + key] = pv;
                continue;
            }
            #pragma unroll
            for (int r = 0; r < 4; r++) {
                int row = row0 + r;
                float v = acc[mt][nt][r];
                if (EPI == 0) {
                    int which = col >> 10;
                    if (which == 0) v *= QSCALE;   // base-2 softmax fold
                    C[(size_t)which * ((size_t)MTOK*1024)
                      + (size_t)row * 1024 + (col & 1023)] = f2bf(v);
                } else if (EPI == 1) {
                    v += bias[col];
                    v = (v > 0.f) ? SS * v
                                  : SS * SA * (exp2f(v * 1.44269504f) - 1.f);
                    C[(size_t)row * N + col] = f2bf(v);
                } else {   // EPI == 3: raw bf16 partial, quarter z
                    C[(size_t)blockIdx.z * ((size_t)MTOK*N)
                      + (size_t)row * N + col] = f2bf(v);
                }
            }
        }
    }
#undef STAGE_TILE
#undef LDAB
#undef MM32
}

// ---------------------------------------------------------------------------
// MFMA flash attention, QBLK=64 (R12-verified; R11's 128 was tail-bound at
// 10.6% occupancy). 64-row Q-tile, 4 waves x 16 q-rows; ping-pong LDS K/V.
// Grid = (SEQ/64, BATCH*NH) = (16, 64) -> 1024 blocks, 3 blocks/CU (41 KB).
// Base-2 fixed-m softmax, ones-MFMA row-sum. V pre-transposed (Vt[bh][d][key]).
// SWAPPED QK^T: S = mfma(A=K, B=Q); P-store = ds_write_b64 packed.
// T2 SWIZZLE on Ks/Vs (both-sides, rule 21): source granule pre-permuted by
// g ^= (row&7); ds_read applies the same XOR. (R8: conflicts 4.18M -> 835K)
// ---------------------------------------------------------------------------
__global__ __launch_bounds__(256) void attn_kernel(
    const short* __restrict__ Q, const short* __restrict__ K,
    const short* __restrict__ Vt, short* __restrict__ CTX)
{
    __shared__ __align__(16) short Ks[2][64*64];    // [key][d], 2 x 8 KB
    __shared__ __align__(16) short Vs[2][64*64];    // [d][key], 2 x 8 KB
    __shared__ __align__(16) short Pl[4][16][72];   // [wave][qrow][key], 9 KB

    const int t    = threadIdx.x;
    const int lane = t & 63;
    const int wave = t >> 6;
    const int quad = lane >> 4;
    const int l15  = lane & 15;
    const int q0 = (gridDim.x - 1 - blockIdx.x) * 64;    // long blocks first
    const int bh = blockIdx.y;
    const int b  = bh >> 4;
    const int h  = bh & 15;

    const size_t headoff = (size_t)b * SEQ * DIM + (size_t)h * DH;
    const short* Qb  = Q + headoff;
    const short* Kb  = K + headoff;
    const short* Vtb = Vt + (size_t)bh * DH * SEQ;   // [d][key]

    const int wrow0 = q0 + wave*16;                  // wave's first q-row

    short8 aq[2];
    #pragma unroll
    for (int c = 0; c < 2; c++)
        aq[c] = *(const short8*)(Qb
            + (size_t)(wrow0 + l15) * DIM + c*32 + quad*8);

    short8 bones;
    {
        short v = (l15 == 0) ? (short)0x3F80 : (short)0;
        #pragma unroll
        for (int e = 0; e < 8; e++) bones[e] = v;
    }

    floatx4 o[4], ol;
    #pragma unroll
    for (int nt = 0; nt < 4; nt++) o[nt] = {0.f, 0.f, 0.f, 0.f};
    ol = {0.f, 0.f, 0.f, 0.f};

    // stage with pre-swizzled source granule: physical granule (t&7) at row
    // r=(t>>3)+p*32 receives logical granule (t&7)^(r&7); p*32 = 0 mod 8.
    const int swz = (((t & 7) ^ ((t >> 3) & 7))) * 8;
    auto stage = [&](int j0, int sb) {
        #pragma unroll
        for (int p = 0; p < 2; p++) {
            async_ld16(Ks[sb] + (t + p*256)*8,
                       Kb + (size_t)(j0 + (t>>3) + p*32) * DIM + swz);
            async_ld16(Vs[sb] + (t + p*256)*8,
                       Vtb + (size_t)((t>>3) + p*32) * SEQ + j0 + swz);
        }
    };

    const int jend = q0 + 64;
    stage(0, 0);
    __syncthreads();

    int sb = 0;
    for (int j0 = 0; j0 < jend; j0 += 64) {
        if (j0 + 64 < jend) stage(j0 + 64, sb ^ 1);

        if (j0 <= wrow0 + 15) {              // not fully masked for this wave
            floatx4 s[4];
            #pragma unroll
            for (int nt = 0; nt < 4; nt++) s[nt] = {0.f, 0.f, 0.f, 0.f};
            // SWAPPED: A = K-frag, B = Q-frag -> C row = key, col = q.
            // K-frag read: row = nt*16+l15, granule (c*4+quad)^(row&7).
            #pragma unroll
            for (int c = 0; c < 2; c++) {
                #pragma unroll
                for (int nt = 0; nt < 4; nt++) {
                    short8 bk = *(const short8*)&Ks[sb][(nt*16 + l15)*64
                                  + ((c*4 + quad) ^ (l15 & 7))*8];
                    s[nt] = __builtin_amdgcn_mfma_f32_16x16x32_bf16(bk, aq[c], s[nt], 0, 0, 0);
                }
            }

            if (j0 + 63 > wrow0) {           // diagonal region: causal mask
                int rowq = wrow0 + l15;                      // q = col
                #pragma unroll
                for (int nt = 0; nt < 4; nt++) {
                    #pragma unroll
                    for (int r = 0; r < 4; r++) {
                        int key = j0 + nt*16 + quad*4 + r;   // key = row
                        if (key > rowq) s[nt][r] = -1.0e38f;
                    }
                }
            }

            // packed P-store: 4 consecutive keys per lane -> one b64 write
            #pragma unroll
            for (int nt = 0; nt < 4; nt++) {
                short4v pv;
                #pragma unroll
                for (int r = 0; r < 4; r++)
                    pv[r] = f2bf(exp2f(s[nt][r]));
                *(short4v*)&Pl[wave][l15][nt*16 + quad*4] = pv;
            }

            #pragma unroll
            for (int c = 0; c < 2; c++) {
                short8 ap = *(const short8*)&Pl[wave][l15][c*32 + quad*8];
                #pragma unroll
                for (int nt = 0; nt < 4; nt++) {
                    // V-frag read: row (=d) = nt*16+l15, same XOR swizzle.
                    short8 bv = *(const short8*)&Vs[sb][(nt*16 + l15)*64
                                  + ((c*4 + quad) ^ (l15 & 7))*8];
                    o[nt] = __builtin_amdgcn_mfma_f32_16x16x32_bf16(ap, bv, o[nt], 0, 0, 0);
                }
                ol = __builtin_amdgcn_mfma_f32_16x16x32_bf16(ap, bones, ol, 0, 0, 0);
            }
        }

        __syncthreads();                     // drains vmcnt after compute
        sb ^= 1;
    }

    float linv[4];
    #pragma unroll
    for (int r = 0; r < 4; r++)
        linv[r] = 1.f / __shfl(ol[r], lane & 48);
    #pragma unroll
    for (int nt = 0; nt < 4; nt++) {
        #pragma unroll
        for (int r = 0; r < 4; r++) {
            int rowq = wrow0 + quad*4 + r;
            int d    = nt*16 + l15;
            CTX[(size_t)b * SEQ * DIM + (size_t)rowq * DIM + h*DH + d]
                = f2bf(o[nt][r] * linv[r]);
        }
    }
}

// ---------------------------------------------------------------------------
// LN1: row LayerNorm over D=1024 of (X fp32 + CTX bf16), bf16 out.
// ---------------------------------------------------------------------------
__global__ __launch_bounds__(256) void ln1_kernel(
    const float* __restrict__ X, const short* __restrict__ ctx,
    const float* __restrict__ g, const float* __restrict__ bvec,
    short* __restrict__ out)
{
    __shared__ float red[8];
    const size_t base = (size_t)blockIdx.x * DIM;
    const int wave = threadIdx.x >> 6;

    float x[4];
    float sum = 0.f, sq = 0.f;
    #pragma unroll
    for (int i = 0; i < 4; i++) {
        int idx = threadIdx.x + i*256;
        float v = X[base + idx] + bf2f(ctx[base + idx]);
        x[i] = v; sum += v; sq += v*v;
    }
    sum = wave_sum(sum); sq = wave_sum(sq);
    if ((threadIdx.x & 63) == 0) { red[wave] = sum; red[4 + wave] = sq; }
    __syncthreads();
    float s1 = red[0] + red[1] + red[2] + red[3];
    float s2 = red[4] + red[5] + red[6] + red[7];
    float mean = s1 * (1.f / DIM);
    float var  = s2 * (1.f / DIM) - mean * mean;
    float rstd = rsqrtf(var + 1e-5f);
    #pragma unroll
    for (int i = 0; i < 4; i++) {
        int idx = threadIdx.x + i*256;
        out[base + idx] = f2bf((x[i] - mean) * rstd * g[idx] + bvec[idx]);
    }
}

// ---------------------------------------------------------------------------
// LN2 fused with split-K reduce: x = P0+P1+P2+P3 (bf16 partials) + bias +
// X1 (residual), then LayerNorm, fp32 out to d_out.
// ---------------------------------------------------------------------------
__global__ __launch_bounds__(256) void ln2_fused(
    const short* __restrict__ P, const float* __restrict__ bias,
    const short* __restrict__ x1, const float* __restrict__ g,
    const float* __restrict__ bvec, float* __restrict__ out)
{
    __shared__ float red[8];
    const size_t base = (size_t)blockIdx.x * DIM;
    const size_t E4 = (size_t)MTOK * 1024;
    const int wave = threadIdx.x >> 6;

    float x[4];
    float sum = 0.f, sq = 0.f;
    #pragma unroll
    for (int i = 0; i < 4; i++) {
        int idx = threadIdx.x + i*256;
        size_t p = base + idx;
        float v = bf2f(P[p]) + bf2f(P[E4 + p]) + bf2f(P[2*E4 + p])
                + bf2f(P[3*E4 + p]) + bias[idx] + bf2f(x1[p]);
        x[i] = v; sum += v; sq += v*v;
    }
    sum = wave_sum(sum); sq = wave_sum(sq);
    if ((threadIdx.x & 63) == 0) { red[wave] = sum; red[4 + wave] = sq; }
    __syncthreads();
    float s1 = red[0] + red[1] + red[2] + red[3];
    float s2 = red[4] + red[5] + red[6] + red[7];
    float mean = s1 * (1.f / DIM);
    float var  = s2 * (1.f / DIM) - mean * mean;
    float rstd = rsqrtf(var + 1e-5f);
    #pragma unroll
    for (int i = 0; i < 4; i++) {
        int idx = threadIdx.x + i*256;
        out[base + idx] = (x[i] - mean) * rstd * g[idx] + bvec[idx];
    }
}

// ---------------------------------------------------------------------------
// Workspace (102 MB -- exactly R2's proven-safe footprint).
// Q | K | Vt contiguous (fused QKV epilogue). P = 4 split-K partials.
// d_out is float* (verified round 4).
// ---------------------------------------------------------------------------
extern "C" void kernel_launch(void* const* d_in, const int* in_sizes, int n_in,
                              void* d_out, int out_size, void* d_ws, size_t ws_size,
                              hipStream_t stream)
{
    const float* X   = (const float*)d_in[0];
    const float* wq  = (const float*)d_in[1];
    const float* wk  = (const float*)d_in[2];
    const float* wv  = (const float*)d_in[3];
    const float* g1  = (const float*)d_in[4];
    const float* b1  = (const float*)d_in[5];
    const float* w1  = (const float*)d_in[6];
    const float* bb1 = (const float*)d_in[7];
    const float* w2  = (const float*)d_in[8];
    const float* bb2 = (const float*)d_in[9];
    const float* g2  = (const float*)d_in[10];
    const float* b2  = (const float*)d_in[11];

    short* ws = (short*)d_ws;
    const size_t E1 = 1048576, E4 = 4194304;
    size_t o = 0;
    short* Xb    = ws + o; o += E4;
    short* wqkvb = ws + o; o += 3*E1;
    short* w1b   = ws + o; o += E4;
    short* w2b   = ws + o; o += E4;
    short* Q     = ws + o; o += E4;   // Q | K | Vt contiguous
    short* Kb    = ws + o; o += E4;
    short* Vt    = ws + o; o += E4;
    short* CTX   = ws + o; o += E4;
    short* X1    = ws + o; o += E4;
    short* P     = ws + o; o += 4*E4; // split-K=4 partials (bf16)
    short* Hf    = Q;                 // 16M elems, overlays Q..CTX

    dim3 blk(256);
    convert_all<<<dim3(7680), blk, 0, stream>>>(
        X, Xb, wq, wqkvb, wk, wqkvb + E1, wv, wqkvb + 2*E1,
        w1, w1b, w2, w2b);

    gemm128d<0><<<dim3(MTOK/128, 3072/128), blk, 0, stream>>>(
        Xb, wqkvb, nullptr, Q, 3072, DIM);
    attn_kernel<<<dim3(SEQ/64, BATCH*NH), blk, 0, stream>>>(Q, Kb, Vt, CTX);
    ln1_kernel<<<dim3(MTOK), blk, 0, stream>>>(X, CTX, g1, b1, X1);
    gemm128d<1><<<dim3(MTOK/128, DFF/128), blk, 0, stream>>>(
        X1, w1b, bb1, Hf, DFF, DIM);
    gemm128d<3><<<dim3(MTOK/128, DIM/128, 4), blk, 0, stream>>>(
        Hf, w2b, nullptr, P, DIM, DFF);
    ln2_fused<<<dim3(MTOK), blk, 0, stream>>>(P, bb2, X1, g2, b2, (float*)d_out);
}

// Round 14
// 258.529 us; speedup vs baseline: 1.1631x; 1.1121x over previous
//
#include <hip/hip_runtime.h>
#include <hip/hip_bf16.h>

#define BATCH 4
#define SEQ   1024
#define DIM   1024
#define NH    16
#define DH    64
#define DFF   4096
#define MTOK  (BATCH*SEQ)   // 4096 token rows

// log2(e)/8 : folded into Q so attention softmax runs in base-2 (exact).
#define QSCALE 0.1803368801111204f

typedef __attribute__((ext_vector_type(8))) short  short8;
typedef __attribute__((ext_vector_type(4))) short  short4v;
typedef __attribute__((ext_vector_type(4))) float  floatx4;
typedef __attribute__((ext_vector_type(4))) float  float4v;
typedef __attribute__((ext_vector_type(4))) int    int4v;

__device__ inline float bf2f(short s) {
    return __uint_as_float(((unsigned int)(unsigned short)s) << 16);
}
__device__ inline short f2bf(float f) {
    __hip_bfloat16 h = __float2bfloat16(f);
    return *reinterpret_cast<short*>(&h);
}

__device__ inline float wave_sum(float v) {
    #pragma unroll
    for (int off = 32; off >= 1; off >>= 1) v += __shfl_xor(v, off);
    return v;
}

// async global->LDS, 16B per lane; LDS dst = wave-uniform base + lane*16.
__device__ inline void async_ld16(short* lds, const short* g) {
    __builtin_amdgcn_global_load_lds(
        (const __attribute__((address_space(1))) void*)g,
        (__attribute__((address_space(3))) void*)lds, 16, 0, 0);
}

// ---------------------------------------------------------------------------
// Fused fp32->bf16 conversion of all 6 tensors in ONE launch.
// ---------------------------------------------------------------------------
__global__ __launch_bounds__(256) void convert_all(
    const float* __restrict__ sX,  short* __restrict__ dX,
    const float* __restrict__ sq,  short* __restrict__ dq,
    const float* __restrict__ sk,  short* __restrict__ dk,
    const float* __restrict__ sv,  short* __restrict__ dv,
    const float* __restrict__ s1,  short* __restrict__ d1,
    const float* __restrict__ s2,  short* __restrict__ d2)
{
    int cid = blockIdx.x * 256 + threadIdx.x;     // 0 .. 1966079
    const float* src; short* dst; int base;
    if      (cid <  524288) { src = sX; dst = dX; base = 0; }
    else if (cid <  655360) { src = sq; dst = dq; base = 524288; }
    else if (cid <  786432) { src = sk; dst = dk; base = 655360; }
    else if (cid <  917504) { src = sv; dst = dv; base = 786432; }
    else if (cid < 1441792) { src = s1; dst = d1; base = 917504; }
    else                    { src = s2; dst = d2; base = 1441792; }
    size_t i = (size_t)(cid - base) * 8;
    float4v f0 = *(const float4v*)(src + i);
    float4v f1 = *(const float4v*)(src + i + 4);
    short8 o;
    o[0]=f2bf(f0[0]); o[1]=f2bf(f0[1]); o[2]=f2bf(f0[2]); o[3]=f2bf(f0[3]);
    o[4]=f2bf(f1[0]); o[5]=f2bf(f1[1]); o[6]=f2bf(f1[2]); o[7]=f2bf(f1[3]);
    *(short8*)(dst + i) = o;
}

// ---------------------------------------------------------------------------
// NT GEMM, 128x128 tile, 16x16x32 MFMA, 2 blocks/CU, __syncthreads-only
// (R11/R13-verified: ~46.5us, conflicts 0). C[M,N]=A[M,K]*B[N,K]^T, bf16,
// fp32 accum. BK=64, 256 thr = 4 waves (2M x 2N), per-wave C=64x64 (16 acc).
// LDS 64 KB: 2 buffers x {A 128x64, B 128x64} bf16, staged LINEARLY by
// global_load_lds, global source granule pre-permuted by the involution
// g ^= (row&7); ds_read applies the same XOR (rule 21).
//
// Per K-tile (ONE barrier): { stage kt+1 -> buf^1 (8x gload_lds);
//   read 16x b128 from buf; 32 MFMA; __syncthreads() }
//
// EPI: 0 = QKV split store (Q pre-scaled by QSCALE; V written TRANSPOSED
//          into Vt[bh][d][key]); 1 = +bias,SELU;
//      3 = split-K bf16 partial store (blockIdx.z selects K quarter)
// ---------------------------------------------------------------------------
template<int EPI>
__global__ __launch_bounds__(256, 2) void gemm128d(
    const short* __restrict__ A, const short* __restrict__ B,
    const float* __restrict__ bias, short* __restrict__ C, int N, int K)
{
    __shared__ __align__(16) short Ls[32768];      // 64 KB

    const int t    = threadIdx.x;                  // 0..255
    const int lane = t & 63;
    const int wave = t >> 6;
    const int quad = lane >> 4;
    const int l15  = lane & 15;
    const int wm   = wave & 1;                     // 0..1
    const int wn   = wave >> 1;                    // 0..1
    const int tm   = blockIdx.x * 128;
    const int tn   = blockIdx.y * 128;

    int kbase = 0, klen = K;
    if (EPI == 3) { klen = K >> 2; kbase = blockIdx.z * klen; }
    const int NT = klen >> 6;                      // K-tiles of 64

    // ---- staging precompute: inst i covers 16B granule G = i*256 + t ----
    // row = G>>3 = i*32 + (t>>3)  (i*32 == 0 mod 8 -> row&7 = (t>>3)&7)
    // physical granule p = t&7 holds logical granule p ^ (row&7).
    const int g8 = (((t & 7) ^ ((t >> 3) & 7)) << 3);
    int offR[4];
    #pragma unroll
    for (int i = 0; i < 4; i++) offR[i] = (i*32 + (t >> 3)) * K + g8;
    const short* Abase = A + (size_t)tm * K + kbase;
    const short* Bbase = B + (size_t)tn * K + kbase;
    short* dstb = &Ls[t * 8];   // + buf*16384 + i*2048 (+8192 for B)

    // ---- frag-read precompute (swizzled ds_read addresses) ----
    const int xa  = (wm*64 + l15) * 64;            // A logical row base
    const int xb  = (wn*64 + l15) * 64;            // B logical row base
    const int sw  = l15 & 7;
    const int xc0 = ((quad ^ sw) << 3);            // ksub c=0 granule
    const int xc1 = (((4 + quad) ^ sw) << 3);      // ksub c=1 granule

    short8 a[4][2], b[4][2];
    floatx4 acc[4][4];
    #pragma unroll
    for (int mt = 0; mt < 4; mt++)
        #pragma unroll
        for (int nt = 0; nt < 4; nt++) acc[mt][nt] = {0.f, 0.f, 0.f, 0.f};

#define STAGE_TILE(buf, k0) do { _Pragma("unroll")                    \
    for (int _i = 0; _i < 4; _i++) {                                  \
        async_ld16(dstb + (buf)*16384 + _i*2048,        Abase + offR[_i] + (k0)); \
        async_ld16(dstb + (buf)*16384 + 8192 + _i*2048, Bbase + offR[_i] + (k0)); \
    } } while (0)

#define LDAB(buf) do { _Pragma("unroll")                              \
    for (int _mt = 0; _mt < 4; _mt++) {                               \
        a[_mt][0] = *(const short8*)&Ls[(buf)*16384 + xa + _mt*1024 + xc0]; \
        a[_mt][1] = *(const short8*)&Ls[(buf)*16384 + xa + _mt*1024 + xc1]; \
        b[_mt][0] = *(const short8*)&Ls[(buf)*16384 + 8192 + xb + _mt*1024 + xc0]; \
        b[_mt][1] = *(const short8*)&Ls[(buf)*16384 + 8192 + xb + _mt*1024 + xc1]; \
    } } while (0)

// 32 MFMA, c outermost so consecutive MFMAs never hit the same accumulator.
#define MM32() do { __builtin_amdgcn_s_setprio(1); _Pragma("unroll")  \
    for (int _c = 0; _c < 2; _c++) { _Pragma("unroll")                \
        for (int _mt = 0; _mt < 4; _mt++) { _Pragma("unroll")         \
            for (int _nn = 0; _nn < 4; _nn++) {                       \
                acc[_mt][_nn] = __builtin_amdgcn_mfma_f32_16x16x32_bf16( \
                    a[_mt][_c], b[_nn][_c], acc[_mt][_nn], 0, 0, 0);  \
            } } }                                                     \
    __builtin_amdgcn_s_setprio(0); } while (0)

    // ---- prologue: stage tile 0 into buf 0, drain + barrier
    STAGE_TILE(0, 0);
    __syncthreads();

    for (int kt = 0; kt < NT; ++kt) {
        const int cur = kt & 1;
        if (kt + 1 < NT) STAGE_TILE(cur ^ 1, (kt + 1) << 6);
        LDAB(cur);                                 // 16x ds_read_b128
        MM32();                                    // compiler waits lgkm
        __syncthreads();                           // drain vm+lgkm; handoff
    }

    const float SS = 1.0507009873554805f;
    const float SA = 1.6732632423543772f;

    #pragma unroll
    for (int mt = 0; mt < 4; mt++) {
        int row0 = tm + wm*64 + mt*16 + quad*4;
        #pragma unroll
        for (int nt = 0; nt < 4; nt++) {
            int col = tn + wn*64 + nt*16 + l15;
            if (EPI == 0 && (col >> 10) == 2) {
                // V: packed transposed store -> Vt[bh][d][key]
                int h = (col >> 6) & 15, d = col & 63;
                int bb = row0 >> 10, key = row0 & 1023;
                short4v pv;
                #pragma unroll
                for (int r = 0; r < 4; r++) pv[r] = f2bf(acc[mt][nt][r]);
                *(short4v*)&C[(size_t)2*MTOK*1024
                    + ((size_t)(bb*16 + h)*64 + d)*1024 + key] = pv;
                continue;
            }
            #pragma unroll
            for (int r = 0; r < 4; r++) {
                int row = row0 + r;
                float v = acc[mt][nt][r];
                if (EPI == 0) {
                    int which = col >> 10;
                    if (which == 0) v *= QSCALE;   // base-2 softmax fold
                    C[(size_t)which * ((size_t)MTOK*1024)
                      + (size_t)row * 1024 + (col & 1023)] = f2bf(v);
                } else if (EPI == 1) {
                    v += bias[col];
                    v = (v > 0.f) ? SS * v
                                  : SS * SA * (exp2f(v * 1.44269504f) - 1.f);
                    C[(size_t)row * N + col] = f2bf(v);
                } else {   // EPI == 3: raw bf16 partial, quarter z
                    C[(size_t)blockIdx.z * ((size_t)MTOK*N)
                      + (size_t)row * N + col] = f2bf(v);
                }
            }
        }
    }
#undef STAGE_TILE
#undef LDAB
#undef MM32
}

// ---------------------------------------------------------------------------
// MFMA flash attention, QBLK=64, XCD-AFFINITY REMAP (R13: FETCH 55MB vs
// ~32MB unique -> ~3.4x K/V HBM re-read because the 16 q-blocks of one head
// round-robin across 8 non-coherent per-XCD L2s; attn is latency-bound on
// the staging chain, so HBM-latency (~900cy) vs L2-hit (~200cy) stage is
// the critical-path delta).
// 1-D grid 1024; hw block lin -> xcd=lin&7, j=lin>>3, bh=xcd*8+(j&7),
// q0=(15-(j>>3))*64 (long blocks first per XCD). All 16 q-blocks of a head
// share one XCD; 8 heads/XCD = 2MB K/V fits the 4MB L2. Bijective.
// 64-row Q-tile, 4 waves x 16 q-rows; ping-pong LDS K/V; base-2 fixed-m
// softmax, ones-MFMA row-sum; V pre-transposed (Vt[bh][d][key]).
// SWAPPED QK^T: S = mfma(A=K, B=Q); P-store = ds_write_b64 packed.
// T2 SWIZZLE on Ks/Vs (both-sides, rule 21).
// ---------------------------------------------------------------------------
__global__ __launch_bounds__(256) void attn_kernel(
    const short* __restrict__ Q, const short* __restrict__ K,
    const short* __restrict__ Vt, short* __restrict__ CTX)
{
    __shared__ __align__(16) short Ks[2][64*64];    // [key][d], 2 x 8 KB
    __shared__ __align__(16) short Vs[2][64*64];    // [d][key], 2 x 8 KB
    __shared__ __align__(16) short Pl[4][16][72];   // [wave][qrow][key], 9 KB

    const int t    = threadIdx.x;
    const int lane = t & 63;
    const int wave = t >> 6;
    const int quad = lane >> 4;
    const int l15  = lane & 15;

    // XCD-affinity remap (8 XCDs, hw XCD ~ lin%8)
    const int lin = blockIdx.x;                  // 0..1023
    const int xcd = lin & 7;
    const int j   = lin >> 3;                    // 0..127
    const int bh  = xcd * 8 + (j & 7);           // head-batch: fixed per XCD
    const int q0  = (15 - (j >> 3)) * 64;        // long blocks first
    const int b  = bh >> 4;
    const int h  = bh & 15;

    const size_t headoff = (size_t)b * SEQ * DIM + (size_t)h * DH;
    const short* Qb  = Q + headoff;
    const short* Kb  = K + headoff;
    const short* Vtb = Vt + (size_t)bh * DH * SEQ;   // [d][key]

    const int wrow0 = q0 + wave*16;                  // wave's first q-row

    short8 aq[2];
    #pragma unroll
    for (int c = 0; c < 2; c++)
        aq[c] = *(const short8*)(Qb
            + (size_t)(wrow0 + l15) * DIM + c*32 + quad*8);

    short8 bones;
    {
        short v = (l15 == 0) ? (short)0x3F80 : (short)0;
        #pragma unroll
        for (int e = 0; e < 8; e++) bones[e] = v;
    }

    floatx4 o[4], ol;
    #pragma unroll
    for (int nt = 0; nt < 4; nt++) o[nt] = {0.f, 0.f, 0.f, 0.f};
    ol = {0.f, 0.f, 0.f, 0.f};

    // stage with pre-swizzled source granule: physical granule (t&7) at row
    // r=(t>>3)+p*32 receives logical granule (t&7)^(r&7); p*32 = 0 mod 8.
    const int swz = (((t & 7) ^ ((t >> 3) & 7))) * 8;
    auto stage = [&](int j0, int sb) {
        #pragma unroll
        for (int p = 0; p < 2; p++) {
            async_ld16(Ks[sb] + (t + p*256)*8,
                       Kb + (size_t)(j0 + (t>>3) + p*32) * DIM + swz);
            async_ld16(Vs[sb] + (t + p*256)*8,
                       Vtb + (size_t)((t>>3) + p*32) * SEQ + j0 + swz);
        }
    };

    const int jend = q0 + 64;
    stage(0, 0);
    __syncthreads();

    int sb = 0;
    for (int j0 = 0; j0 < jend; j0 += 64) {
        if (j0 + 64 < jend) stage(j0 + 64, sb ^ 1);

        if (j0 <= wrow0 + 15) {              // not fully masked for this wave
            floatx4 s[4];
            #pragma unroll
            for (int nt = 0; nt < 4; nt++) s[nt] = {0.f, 0.f, 0.f, 0.f};
            // SWAPPED: A = K-frag, B = Q-frag -> C row = key, col = q.
            // K-frag read: row = nt*16+l15, granule (c*4+quad)^(row&7).
            #pragma unroll
            for (int c = 0; c < 2; c++) {
                #pragma unroll
                for (int nt = 0; nt < 4; nt++) {
                    short8 bk = *(const short8*)&Ks[sb][(nt*16 + l15)*64
                                  + ((c*4 + quad) ^ (l15 & 7))*8];
                    s[nt] = __builtin_amdgcn_mfma_f32_16x16x32_bf16(bk, aq[c], s[nt], 0, 0, 0);
                }
            }

            if (j0 + 63 > wrow0) {           // diagonal region: causal mask
                int rowq = wrow0 + l15;                      // q = col
                #pragma unroll
                for (int nt = 0; nt < 4; nt++) {
                    #pragma unroll
                    for (int r = 0; r < 4; r++) {
                        int key = j0 + nt*16 + quad*4 + r;   // key = row
                        if (key > rowq) s[nt][r] = -1.0e38f;
                    }
                }
            }

            // packed P-store: 4 consecutive keys per lane -> one b64 write
            #pragma unroll
            for (int nt = 0; nt < 4; nt++) {
                short4v pv;
                #pragma unroll
                for (int r = 0; r < 4; r++)
                    pv[r] = f2bf(exp2f(s[nt][r]));
                *(short4v*)&Pl[wave][l15][nt*16 + quad*4] = pv;
            }

            #pragma unroll
            for (int c = 0; c < 2; c++) {
                short8 ap = *(const short8*)&Pl[wave][l15][c*32 + quad*8];
                #pragma unroll
                for (int nt = 0; nt < 4; nt++) {
                    // V-frag read: row (=d) = nt*16+l15, same XOR swizzle.
                    short8 bv = *(const short8*)&Vs[sb][(nt*16 + l15)*64
                                  + ((c*4 + quad) ^ (l15 & 7))*8];
                    o[nt] = __builtin_amdgcn_mfma_f32_16x16x32_bf16(ap, bv, o[nt], 0, 0, 0);
                }
                ol = __builtin_amdgcn_mfma_f32_16x16x32_bf16(ap, bones, ol, 0, 0, 0);
            }
        }

        __syncthreads();                     // drains vmcnt after compute
        sb ^= 1;
    }

    float linv[4];
    #pragma unroll
    for (int r = 0; r < 4; r++)
        linv[r] = 1.f / __shfl(ol[r], lane & 48);
    #pragma unroll
    for (int nt = 0; nt < 4; nt++) {
        #pragma unroll
        for (int r = 0; r < 4; r++) {
            int rowq = wrow0 + quad*4 + r;
            int d    = nt*16 + l15;
            CTX[(size_t)b * SEQ * DIM + (size_t)rowq * DIM + h*DH + d]
                = f2bf(o[nt][r] * linv[r]);
        }
    }
}

// ---------------------------------------------------------------------------
// LN1: row LayerNorm over D=1024 of (X fp32 + CTX bf16), bf16 out.
// ---------------------------------------------------------------------------
__global__ __launch_bounds__(256) void ln1_kernel(
    const float* __restrict__ X, const short* __restrict__ ctx,
    const float* __restrict__ g, const float* __restrict__ bvec,
    short* __restrict__ out)
{
    __shared__ float red[8];
    const size_t base = (size_t)blockIdx.x * DIM;
    const int wave = threadIdx.x >> 6;

    float x[4];
    float sum = 0.f, sq = 0.f;
    #pragma unroll
    for (int i = 0; i < 4; i++) {
        int idx = threadIdx.x + i*256;
        float v = X[base + idx] + bf2f(ctx[base + idx]);
        x[i] = v; sum += v; sq += v*v;
    }
    sum = wave_sum(sum); sq = wave_sum(sq);
    if ((threadIdx.x & 63) == 0) { red[wave] = sum; red[4 + wave] = sq; }
    __syncthreads();
    float s1 = red[0] + red[1] + red[2] + red[3];
    float s2 = red[4] + red[5] + red[6] + red[7];
    float mean = s1 * (1.f / DIM);
    float var  = s2 * (1.f / DIM) - mean * mean;
    float rstd = rsqrtf(var + 1e-5f);
    #pragma unroll
    for (int i = 0; i < 4; i++) {
        int idx = threadIdx.x + i*256;
        out[base + idx] = f2bf((x[i] - mean) * rstd * g[idx] + bvec[idx]);
    }
}

// ---------------------------------------------------------------------------
// LN2 fused with split-K reduce: x = P0+P1+P2+P3 (bf16 partials) + bias +
// X1 (residual), then LayerNorm, fp32 out to d_out.
// ---------------------------------------------------------------------------
__global__ __launch_bounds__(256) void ln2_fused(
    const short* __restrict__ P, const float* __restrict__ bias,
    const short* __restrict__ x1, const float* __restrict__ g,
    const float* __restrict__ bvec, float* __restrict__ out)
{
    __shared__ float red[8];
    const size_t base = (size_t)blockIdx.x * DIM;
    const size_t E4 = (size_t)MTOK * 1024;
    const int wave = threadIdx.x >> 6;

    float x[4];
    float sum = 0.f, sq = 0.f;
    #pragma unroll
    for (int i = 0; i < 4; i++) {
        int idx = threadIdx.x + i*256;
        size_t p = base + idx;
        float v = bf2f(P[p]) + bf2f(P[E4 + p]) + bf2f(P[2*E4 + p])
                + bf2f(P[3*E4 + p]) + bias[idx] + bf2f(x1[p]);
        x[i] = v; sum += v; sq += v*v;
    }
    sum = wave_sum(sum); sq = wave_sum(sq);
    if ((threadIdx.x & 63) == 0) { red[wave] = sum; red[4 + wave] = sq; }
    __syncthreads();
    float s1 = red[0] + red[1] + red[2] + red[3];
    float s2 = red[4] + red[5] + red[6] + red[7];
    float mean = s1 * (1.f / DIM);
    float var  = s2 * (1.f / DIM) - mean * mean;
    float rstd = rsqrtf(var + 1e-5f);
    #pragma unroll
    for (int i = 0; i < 4; i++) {
        int idx = threadIdx.x + i*256;
        out[base + idx] = (x[i] - mean) * rstd * g[idx] + bvec[idx];
    }
}

// ---------------------------------------------------------------------------
// Workspace (102 MB -- exactly R2's proven-safe footprint).
// Q | K | Vt contiguous (fused QKV epilogue). P = 4 split-K partials.
// d_out is float* (verified round 4).
// ---------------------------------------------------------------------------
extern "C" void kernel_launch(void* const* d_in, const int* in_sizes, int n_in,
                              void* d_out, int out_size, void* d_ws, size_t ws_size,
                              hipStream_t stream)
{
    const float* X   = (const float*)d_in[0];
    const float* wq  = (const float*)d_in[1];
    const float* wk  = (const float*)d_in[2];
    const float* wv  = (const float*)d_in[3];
    const float* g1  = (const float*)d_in[4];
    const float* b1  = (const float*)d_in[5];
    const float* w1  = (const float*)d_in[6];
    const float* bb1 = (const float*)d_in[7];
    const float* w2  = (const float*)d_in[8];
    const float* bb2 = (const float*)d_in[9];
    const float* g2  = (const float*)d_in[10];
    const float* b2  = (const float*)d_in[11];

    short* ws = (short*)d_ws;
    const size_t E1 = 1048576, E4 = 4194304;
    size_t o = 0;
    short* Xb    = ws + o; o += E4;
    short* wqkvb = ws + o; o += 3*E1;
    short* w1b   = ws + o; o += E4;
    short* w2b   = ws + o; o += E4;
    short* Q     = ws + o; o += E4;   // Q | K | Vt contiguous
    short* Kb    = ws + o; o += E4;
    short* Vt    = ws + o; o += E4;
    short* CTX   = ws + o; o += E4;
    short* X1    = ws + o; o += E4;
    short* P     = ws + o; o += 4*E4; // split-K=4 partials (bf16)
    short* Hf    = Q;                 // 16M elems, overlays Q..CTX

    dim3 blk(256);
    convert_all<<<dim3(7680), blk, 0, stream>>>(
        X, Xb, wq, wqkvb, wk, wqkvb + E1, wv, wqkvb + 2*E1,
        w1, w1b, w2, w2b);

    gemm128d<0><<<dim3(MTOK/128, 3072/128), blk, 0, stream>>>(
        Xb, wqkvb, nullptr, Q, 3072, DIM);
    attn_kernel<<<dim3(SEQ/64 * BATCH*NH), blk, 0, stream>>>(Q, Kb, Vt, CTX);
    ln1_kernel<<<dim3(MTOK), blk, 0, stream>>>(X, CTX, g1, b1, X1);
    gemm128d<1><<<dim3(MTOK/128, DFF/128), blk, 0, stream>>>(
        X1, w1b, bb1, Hf, DFF, DIM);
    gemm128d<3><<<dim3(MTOK/128, DIM/128, 4), blk, 0, stream>>>(
        Hf, w2b, nullptr, P, DIM, DFF);
    ln2_fused<<<dim3(MTOK), blk, 0, stream>>>(P, bb2, X1, g2, b2, (float*)d_out);
}

// Round 15
// 254.330 us; speedup vs baseline: 1.1823x; 1.0165x over previous
//
#include <hip/hip_runtime.h>
#include <hip/hip_bf16.h>

#define BATCH 4
#define SEQ   1024
#define DIM   1024
#define NH    16
#define DH    64
#define DFF   4096
#define MTOK  (BATCH*SEQ)   // 4096 token rows

// log2(e)/8 : folded into Q so attention softmax runs in base-2 (exact).
#define QSCALE 0.1803368801111204f

typedef __attribute__((ext_vector_type(8))) short  short8;
typedef __attribute__((ext_vector_type(4))) short  short4v;
typedef __attribute__((ext_vector_type(4))) float  floatx4;
typedef __attribute__((ext_vector_type(4))) float  float4v;
typedef __attribute__((ext_vector_type(4))) int    int4v;

__device__ inline float bf2f(short s) {
    return __uint_as_float(((unsigned int)(unsigned short)s) << 16);
}
__device__ inline short f2bf(float f) {
    __hip_bfloat16 h = __float2bfloat16(f);
    return *reinterpret_cast<short*>(&h);
}

__device__ inline float wave_sum(float v) {
    #pragma unroll
    for (int off = 32; off >= 1; off >>= 1) v += __shfl_xor(v, off);
    return v;
}

// async global->LDS, 16B per lane; LDS dst = wave-uniform base + lane*16.
__device__ inline void async_ld16(short* lds, const short* g) {
    __builtin_amdgcn_global_load_lds(
        (const __attribute__((address_space(1))) void*)g,
        (__attribute__((address_space(3))) void*)lds, 16, 0, 0);
}

// ---------------------------------------------------------------------------
// Fused fp32->bf16 conversion of all 6 tensors in ONE launch.
// ---------------------------------------------------------------------------
__global__ __launch_bounds__(256) void convert_all(
    const float* __restrict__ sX,  short* __restrict__ dX,
    const float* __restrict__ sq,  short* __restrict__ dq,
    const float* __restrict__ sk,  short* __restrict__ dk,
    const float* __restrict__ sv,  short* __restrict__ dv,
    const float* __restrict__ s1,  short* __restrict__ d1,
    const float* __restrict__ s2,  short* __restrict__ d2)
{
    int cid = blockIdx.x * 256 + threadIdx.x;     // 0 .. 1966079
    const float* src; short* dst; int base;
    if      (cid <  524288) { src = sX; dst = dX; base = 0; }
    else if (cid <  655360) { src = sq; dst = dq; base = 524288; }
    else if (cid <  786432) { src = sk; dst = dk; base = 655360; }
    else if (cid <  917504) { src = sv; dst = dv; base = 786432; }
    else if (cid < 1441792) { src = s1; dst = d1; base = 917504; }
    else                    { src = s2; dst = d2; base = 1441792; }
    size_t i = (size_t)(cid - base) * 8;
    float4v f0 = *(const float4v*)(src + i);
    float4v f1 = *(const float4v*)(src + i + 4);
    short8 o;
    o[0]=f2bf(f0[0]); o[1]=f2bf(f0[1]); o[2]=f2bf(f0[2]); o[3]=f2bf(f0[3]);
    o[4]=f2bf(f1[0]); o[5]=f2bf(f1[1]); o[6]=f2bf(f1[2]); o[7]=f2bf(f1[3]);
    *(short8*)(dst + i) = o;
}

// ---------------------------------------------------------------------------
// NT GEMM, 128x128 tile, 16x16x32 MFMA, 2 blocks/CU, __syncthreads-only
// (R11/R13/R14-verified: ~46.5us, conflicts 0). C[M,N]=A[M,K]*B[N,K]^T,
// bf16, fp32 accum. BK=64, 256 thr = 4 waves (2M x 2N), per-wave 64x64.
// LDS 64 KB: 2 buffers x {A 128x64, B 128x64} bf16, staged LINEARLY by
// global_load_lds, global source granule pre-permuted by the involution
// g ^= (row&7); ds_read applies the same XOR (rule 21).
//
// Per K-tile (ONE barrier): { stage kt+1 -> buf^1 (8x gload_lds);
//   read 16x b128 from buf; 32 MFMA; __syncthreads() }
//
// EPI: 0 = QKV split store (Q pre-scaled by QSCALE; V written TRANSPOSED
//          into Vt[bh][d][key]); 1 = +bias,SELU;
//      3 = split-K=2 bf16 partial store (blockIdx.z selects K HALF --
//          R15: was quarters; halves partial traffic, NT 16->32, and
//          512 blocks = exactly 2/CU with no tail round)
// ---------------------------------------------------------------------------
template<int EPI>
__global__ __launch_bounds__(256, 2) void gemm128d(
    const short* __restrict__ A, const short* __restrict__ B,
    const float* __restrict__ bias, short* __restrict__ C, int N, int K)
{
    __shared__ __align__(16) short Ls[32768];      // 64 KB

    const int t    = threadIdx.x;                  // 0..255
    const int lane = t & 63;
    const int wave = t >> 6;
    const int quad = lane >> 4;
    const int l15  = lane & 15;
    const int wm   = wave & 1;                     // 0..1
    const int wn   = wave >> 1;                    // 0..1
    const int tm   = blockIdx.x * 128;
    const int tn   = blockIdx.y * 128;

    int kbase = 0, klen = K;
    if (EPI == 3) { klen = K >> 1; kbase = blockIdx.z * klen; }
    const int NT = klen >> 6;                      // K-tiles of 64

    // ---- staging precompute: inst i covers 16B granule G = i*256 + t ----
    // row = G>>3 = i*32 + (t>>3)  (i*32 == 0 mod 8 -> row&7 = (t>>3)&7)
    // physical granule p = t&7 holds logical granule p ^ (row&7).
    const int g8 = (((t & 7) ^ ((t >> 3) & 7)) << 3);
    int offR[4];
    #pragma unroll
    for (int i = 0; i < 4; i++) offR[i] = (i*32 + (t >> 3)) * K + g8;
    const short* Abase = A + (size_t)tm * K + kbase;
    const short* Bbase = B + (size_t)tn * K + kbase;
    short* dstb = &Ls[t * 8];   // + buf*16384 + i*2048 (+8192 for B)

    // ---- frag-read precompute (swizzled ds_read addresses) ----
    const int xa  = (wm*64 + l15) * 64;            // A logical row base
    const int xb  = (wn*64 + l15) * 64;            // B logical row base
    const int sw  = l15 & 7;
    const int xc0 = ((quad ^ sw) << 3);            // ksub c=0 granule
    const int xc1 = (((4 + quad) ^ sw) << 3);      // ksub c=1 granule

    short8 a[4][2], b[4][2];
    floatx4 acc[4][4];
    #pragma unroll
    for (int mt = 0; mt < 4; mt++)
        #pragma unroll
        for (int nt = 0; nt < 4; nt++) acc[mt][nt] = {0.f, 0.f, 0.f, 0.f};

#define STAGE_TILE(buf, k0) do { _Pragma("unroll")                    \
    for (int _i = 0; _i < 4; _i++) {                                  \
        async_ld16(dstb + (buf)*16384 + _i*2048,        Abase + offR[_i] + (k0)); \
        async_ld16(dstb + (buf)*16384 + 8192 + _i*2048, Bbase + offR[_i] + (k0)); \
    } } while (0)

#define LDAB(buf) do { _Pragma("unroll")                              \
    for (int _mt = 0; _mt < 4; _mt++) {                               \
        a[_mt][0] = *(const short8*)&Ls[(buf)*16384 + xa + _mt*1024 + xc0]; \
        a[_mt][1] = *(const short8*)&Ls[(buf)*16384 + xa + _mt*1024 + xc1]; \
        b[_mt][0] = *(const short8*)&Ls[(buf)*16384 + 8192 + xb + _mt*1024 + xc0]; \
        b[_mt][1] = *(const short8*)&Ls[(buf)*16384 + 8192 + xb + _mt*1024 + xc1]; \
    } } while (0)

// 32 MFMA, c outermost so consecutive MFMAs never hit the same accumulator.
#define MM32() do { __builtin_amdgcn_s_setprio(1); _Pragma("unroll")  \
    for (int _c = 0; _c < 2; _c++) { _Pragma("unroll")                \
        for (int _mt = 0; _mt < 4; _mt++) { _Pragma("unroll")         \
            for (int _nn = 0; _nn < 4; _nn++) {                       \
                acc[_mt][_nn] = __builtin_amdgcn_mfma_f32_16x16x32_bf16( \
                    a[_mt][_c], b[_nn][_c], acc[_mt][_nn], 0, 0, 0);  \
            } } }                                                     \
    __builtin_amdgcn_s_setprio(0); } while (0)

    // ---- prologue: stage tile 0 into buf 0, drain + barrier
    STAGE_TILE(0, 0);
    __syncthreads();

    for (int kt = 0; kt < NT; ++kt) {
        const int cur = kt & 1;
        if (kt + 1 < NT) STAGE_TILE(cur ^ 1, (kt + 1) << 6);
        LDAB(cur);                                 // 16x ds_read_b128
        MM32();                                    // compiler waits lgkm
        __syncthreads();                           // drain vm+lgkm; handoff
    }

    const float SS = 1.0507009873554805f;
    const float SA = 1.6732632423543772f;

    #pragma unroll
    for (int mt = 0; mt < 4; mt++) {
        int row0 = tm + wm*64 + mt*16 + quad*4;
        #pragma unroll
        for (int nt = 0; nt < 4; nt++) {
            int col = tn + wn*64 + nt*16 + l15;
            if (EPI == 0 && (col >> 10) == 2) {
                // V: packed transposed store -> Vt[bh][d][key]
                int h = (col >> 6) & 15, d = col & 63;
                int bb = row0 >> 10, key = row0 & 1023;
                short4v pv;
                #pragma unroll
                for (int r = 0; r < 4; r++) pv[r] = f2bf(acc[mt][nt][r]);
                *(short4v*)&C[(size_t)2*MTOK*1024
                    + ((size_t)(bb*16 + h)*64 + d)*1024 + key] = pv;
                continue;
            }
            #pragma unroll
            for (int r = 0; r < 4; r++) {
                int row = row0 + r;
                float v = acc[mt][nt][r];
                if (EPI == 0) {
                    int which = col >> 10;
                    if (which == 0) v *= QSCALE;   // base-2 softmax fold
                    C[(size_t)which * ((size_t)MTOK*1024)
                      + (size_t)row * 1024 + (col & 1023)] = f2bf(v);
                } else if (EPI == 1) {
                    v += bias[col];
                    v = (v > 0.f) ? SS * v
                                  : SS * SA * (exp2f(v * 1.44269504f) - 1.f);
                    C[(size_t)row * N + col] = f2bf(v);
                } else {   // EPI == 3: raw bf16 partial, half z
                    C[(size_t)blockIdx.z * ((size_t)MTOK*N)
                      + (size_t)row * N + col] = f2bf(v);
                }
            }
        }
    }
#undef STAGE_TILE
#undef LDAB
#undef MM32
}

// ---------------------------------------------------------------------------
// MFMA flash attention, QBLK=64, XCD-AFFINITY REMAP (R14-verified: the 16
// q-blocks of a head share one XCD's L2 -> K/V staging hits L2 not HBM;
// total dropped 287.5 -> 258.5us).
// 1-D grid 1024; hw block lin -> xcd=lin&7, j=lin>>3, bh=xcd*8+(j&7),
// q0=(15-(j>>3))*64 (long blocks first per XCD). Bijective.
// 64-row Q-tile, 4 waves x 16 q-rows; ping-pong LDS K/V; base-2 fixed-m
// softmax, ones-MFMA row-sum; V pre-transposed (Vt[bh][d][key]).
// SWAPPED QK^T: S = mfma(A=K, B=Q); P-store = ds_write_b64 packed.
// T2 SWIZZLE on Ks/Vs (both-sides, rule 21).
// ---------------------------------------------------------------------------
__global__ __launch_bounds__(256) void attn_kernel(
    const short* __restrict__ Q, const short* __restrict__ K,
    const short* __restrict__ Vt, short* __restrict__ CTX)
{
    __shared__ __align__(16) short Ks[2][64*64];    // [key][d], 2 x 8 KB
    __shared__ __align__(16) short Vs[2][64*64];    // [d][key], 2 x 8 KB
    __shared__ __align__(16) short Pl[4][16][72];   // [wave][qrow][key], 9 KB

    const int t    = threadIdx.x;
    const int lane = t & 63;
    const int wave = t >> 6;
    const int quad = lane >> 4;
    const int l15  = lane & 15;

    // XCD-affinity remap (8 XCDs, hw XCD ~ lin%8)
    const int lin = blockIdx.x;                  // 0..1023
    const int xcd = lin & 7;
    const int j   = lin >> 3;                    // 0..127
    const int bh  = xcd * 8 + (j & 7);           // head-batch: fixed per XCD
    const int q0  = (15 - (j >> 3)) * 64;        // long blocks first
    const int b  = bh >> 4;
    const int h  = bh & 15;

    const size_t headoff = (size_t)b * SEQ * DIM + (size_t)h * DH;
    const short* Qb  = Q + headoff;
    const short* Kb  = K + headoff;
    const short* Vtb = Vt + (size_t)bh * DH * SEQ;   // [d][key]

    const int wrow0 = q0 + wave*16;                  // wave's first q-row

    short8 aq[2];
    #pragma unroll
    for (int c = 0; c < 2; c++)
        aq[c] = *(const short8*)(Qb
            + (size_t)(wrow0 + l15) * DIM + c*32 + quad*8);

    short8 bones;
    {
        short v = (l15 == 0) ? (short)0x3F80 : (short)0;
        #pragma unroll
        for (int e = 0; e < 8; e++) bones[e] = v;
    }

    floatx4 o[4], ol;
    #pragma unroll
    for (int nt = 0; nt < 4; nt++) o[nt] = {0.f, 0.f, 0.f, 0.f};
    ol = {0.f, 0.f, 0.f, 0.f};

    // stage with pre-swizzled source granule: physical granule (t&7) at row
    // r=(t>>3)+p*32 receives logical granule (t&7)^(r&7); p*32 = 0 mod 8.
    const int swz = (((t & 7) ^ ((t >> 3) & 7))) * 8;
    auto stage = [&](int j0, int sb) {
        #pragma unroll
        for (int p = 0; p < 2; p++) {
            async_ld16(Ks[sb] + (t + p*256)*8,
                       Kb + (size_t)(j0 + (t>>3) + p*32) * DIM + swz);
            async_ld16(Vs[sb] + (t + p*256)*8,
                       Vtb + (size_t)((t>>3) + p*32) * SEQ + j0 + swz);
        }
    };

    const int jend = q0 + 64;
    stage(0, 0);
    __syncthreads();

    int sb = 0;
    for (int j0 = 0; j0 < jend; j0 += 64) {
        if (j0 + 64 < jend) stage(j0 + 64, sb ^ 1);

        if (j0 <= wrow0 + 15) {              // not fully masked for this wave
            floatx4 s[4];
            #pragma unroll
            for (int nt = 0; nt < 4; nt++) s[nt] = {0.f, 0.f, 0.f, 0.f};
            // SWAPPED: A = K-frag, B = Q-frag -> C row = key, col = q.
            // K-frag read: row = nt*16+l15, granule (c*4+quad)^(row&7).
            #pragma unroll
            for (int c = 0; c < 2; c++) {
                #pragma unroll
                for (int nt = 0; nt < 4; nt++) {
                    short8 bk = *(const short8*)&Ks[sb][(nt*16 + l15)*64
                                  + ((c*4 + quad) ^ (l15 & 7))*8];
                    s[nt] = __builtin_amdgcn_mfma_f32_16x16x32_bf16(bk, aq[c], s[nt], 0, 0, 0);
                }
            }

            if (j0 + 63 > wrow0) {           // diagonal region: causal mask
                int rowq = wrow0 + l15;                      // q = col
                #pragma unroll
                for (int nt = 0; nt < 4; nt++) {
                    #pragma unroll
                    for (int r = 0; r < 4; r++) {
                        int key = j0 + nt*16 + quad*4 + r;   // key = row
                        if (key > rowq) s[nt][r] = -1.0e38f;
                    }
                }
            }

            // packed P-store: 4 consecutive keys per lane -> one b64 write
            #pragma unroll
            for (int nt = 0; nt < 4; nt++) {
                short4v pv;
                #pragma unroll
                for (int r = 0; r < 4; r++)
                    pv[r] = f2bf(exp2f(s[nt][r]));
                *(short4v*)&Pl[wave][l15][nt*16 + quad*4] = pv;
            }

            #pragma unroll
            for (int c = 0; c < 2; c++) {
                short8 ap = *(const short8*)&Pl[wave][l15][c*32 + quad*8];
                #pragma unroll
                for (int nt = 0; nt < 4; nt++) {
                    // V-frag read: row (=d) = nt*16+l15, same XOR swizzle.
                    short8 bv = *(const short8*)&Vs[sb][(nt*16 + l15)*64
                                  + ((c*4 + quad) ^ (l15 & 7))*8];
                    o[nt] = __builtin_amdgcn_mfma_f32_16x16x32_bf16(ap, bv, o[nt], 0, 0, 0);
                }
                ol = __builtin_amdgcn_mfma_f32_16x16x32_bf16(ap, bones, ol, 0, 0, 0);
            }
        }

        __syncthreads();                     // drains vmcnt after compute
        sb ^= 1;
    }

    float linv[4];
    #pragma unroll
    for (int r = 0; r < 4; r++)
        linv[r] = 1.f / __shfl(ol[r], lane & 48);
    #pragma unroll
    for (int nt = 0; nt < 4; nt++) {
        #pragma unroll
        for (int r = 0; r < 4; r++) {
            int rowq = wrow0 + quad*4 + r;
            int d    = nt*16 + l15;
            CTX[(size_t)b * SEQ * DIM + (size_t)rowq * DIM + h*DH + d]
                = f2bf(o[nt][r] * linv[r]);
        }
    }
}

// ---------------------------------------------------------------------------
// LN1: row LayerNorm over D=1024 of (X fp32 + CTX bf16), bf16 out.
// ---------------------------------------------------------------------------
__global__ __launch_bounds__(256) void ln1_kernel(
    const float* __restrict__ X, const short* __restrict__ ctx,
    const float* __restrict__ g, const float* __restrict__ bvec,
    short* __restrict__ out)
{
    __shared__ float red[8];
    const size_t base = (size_t)blockIdx.x * DIM;
    const int wave = threadIdx.x >> 6;

    float x[4];
    float sum = 0.f, sq = 0.f;
    #pragma unroll
    for (int i = 0; i < 4; i++) {
        int idx = threadIdx.x + i*256;
        float v = X[base + idx] + bf2f(ctx[base + idx]);
        x[i] = v; sum += v; sq += v*v;
    }
    sum = wave_sum(sum); sq = wave_sum(sq);
    if ((threadIdx.x & 63) == 0) { red[wave] = sum; red[4 + wave] = sq; }
    __syncthreads();
    float s1 = red[0] + red[1] + red[2] + red[3];
    float s2 = red[4] + red[5] + red[6] + red[7];
    float mean = s1 * (1.f / DIM);
    float var  = s2 * (1.f / DIM) - mean * mean;
    float rstd = rsqrtf(var + 1e-5f);
    #pragma unroll
    for (int i = 0; i < 4; i++) {
        int idx = threadIdx.x + i*256;
        out[base + idx] = f2bf((x[i] - mean) * rstd * g[idx] + bvec[idx]);
    }
}

// ---------------------------------------------------------------------------
// LN2 fused with split-K=2 reduce: x = P0+P1 (bf16 partials) + bias +
// X1 (residual), then LayerNorm, fp32 out to d_out.
// ---------------------------------------------------------------------------
__global__ __launch_bounds__(256) void ln2_fused(
    const short* __restrict__ P, const float* __restrict__ bias,
    const short* __restrict__ x1, const float* __restrict__ g,
    const float* __restrict__ bvec, float* __restrict__ out)
{
    __shared__ float red[8];
    const size_t base = (size_t)blockIdx.x * DIM;
    const size_t E4 = (size_t)MTOK * 1024;
    const int wave = threadIdx.x >> 6;

    float x[4];
    float sum = 0.f, sq = 0.f;
    #pragma unroll
    for (int i = 0; i < 4; i++) {
        int idx = threadIdx.x + i*256;
        size_t p = base + idx;
        float v = bf2f(P[p]) + bf2f(P[E4 + p]) + bias[idx] + bf2f(x1[p]);
        x[i] = v; sum += v; sq += v*v;
    }
    sum = wave_sum(sum); sq = wave_sum(sq);
    if ((threadIdx.x & 63) == 0) { red[wave] = sum; red[4 + wave] = sq; }
    __syncthreads();
    float s1 = red[0] + red[1] + red[2] + red[3];
    float s2 = red[4] + red[5] + red[6] + red[7];
    float mean = s1 * (1.f / DIM);
    float var  = s2 * (1.f / DIM) - mean * mean;
    float rstd = rsqrtf(var + 1e-5f);
    #pragma unroll
    for (int i = 0; i < 4; i++) {
        int idx = threadIdx.x + i*256;
        out[base + idx] = (x[i] - mean) * rstd * g[idx] + bvec[idx];
    }
}

// ---------------------------------------------------------------------------
// Workspace (102 MB -- exactly R2's proven-safe footprint).
// Q | K | Vt contiguous (fused QKV epilogue). P = 2 split-K partials
// (allocation unchanged; upper half unused).
// d_out is float* (verified round 4).
// ---------------------------------------------------------------------------
extern "C" void kernel_launch(void* const* d_in, const int* in_sizes, int n_in,
                              void* d_out, int out_size, void* d_ws, size_t ws_size,
                              hipStream_t stream)
{
    const float* X   = (const float*)d_in[0];
    const float* wq  = (const float*)d_in[1];
    const float* wk  = (const float*)d_in[2];
    const float* wv  = (const float*)d_in[3];
    const float* g1  = (const float*)d_in[4];
    const float* b1  = (const float*)d_in[5];
    const float* w1  = (const float*)d_in[6];
    const float* bb1 = (const float*)d_in[7];
    const float* w2  = (const float*)d_in[8];
    const float* bb2 = (const float*)d_in[9];
    const float* g2  = (const float*)d_in[10];
    const float* b2  = (const float*)d_in[11];

    short* ws = (short*)d_ws;
    const size_t E1 = 1048576, E4 = 4194304;
    size_t o = 0;
    short* Xb    = ws + o; o += E4;
    short* wqkvb = ws + o; o += 3*E1;
    short* w1b   = ws + o; o += E4;
    short* w2b   = ws + o; o += E4;
    short* Q     = ws + o; o += E4;   // Q | K | Vt contiguous
    short* Kb    = ws + o; o += E4;
    short* Vt    = ws + o; o += E4;
    short* CTX   = ws + o; o += E4;
    short* X1    = ws + o; o += E4;
    short* P     = ws + o; o += 4*E4; // split-K partials (bf16; 2 used)
    short* Hf    = Q;                 // 16M elems, overlays Q..CTX

    dim3 blk(256);
    convert_all<<<dim3(7680), blk, 0, stream>>>(
        X, Xb, wq, wqkvb, wk, wqkvb + E1, wv, wqkvb + 2*E1,
        w1, w1b, w2, w2b);

    gemm128d<0><<<dim3(MTOK/128, 3072/128), blk, 0, stream>>>(
        Xb, wqkvb, nullptr, Q, 3072, DIM);
    attn_kernel<<<dim3(SEQ/64 * BATCH*NH), blk, 0, stream>>>(Q, Kb, Vt, CTX);
    ln1_kernel<<<dim3(MTOK), blk, 0, stream>>>(X, CTX, g1, b1, X1);
    gemm128d<1><<<dim3(MTOK/128, DFF/128), blk, 0, stream>>>(
        X1, w1b, bb1, Hf, DFF, DIM);
    gemm128d<3><<<dim3(MTOK/128, DIM/128, 2), blk, 0, stream>>>(
        Hf, w2b, nullptr, P, DIM, DFF);
    ln2_fused<<<dim3(MTOK), blk, 0, stream>>>(P, bb2, X1, g2, b2, (float*)d_out);
}